// Round 16
// baseline (65.318 us; speedup 1.0000x reference)
//
#include <hip/hip_runtime.h>

// AdaptiveEmbedding: VOCAB=50000, cutoffs [20000,40000], EMBED_DIM=1024, pad=1
// cluster 0: ids [0,20000)     -> emb0 [20000,1024], direct f32 gather
// cluster 1: ids [20000,40000) -> emb1 [20000,256]  @ proj1[1024,256]^T  (bf16 MFMA)
// cluster 2: ids [40000,50000) -> emb2 [10000,64]   @ proj2[1024,64]^T   (bf16 MFMA)
//
// Round 16: split by REGISTER CLASS. copyprep_k (<=64 regs -> 32 waves/CU)
// carries classify + cvt + all cluster-0 copy (60% of bytes) at full
// occupancy; gemm_k (128 unified regs, 66KB LDS -> 16 waves/CU) does the two
// MFMA gemms with XCD role rotation. In the old fused kernel the gemm role's
// register budget capped the copy stream at half occupancy (r9's null LDS
// experiment is explained by this same cap).

constexpr int NTOK = 8 * 4096;
constexpr int C1 = 20000;
constexpr int C2 = 40000;
constexpr int DIM = 1024;
constexpr int PAD = 1;
constexpr int K1 = 256, K2 = 64;
constexpr int NP1 = DIM * K1;
constexpr int NP2 = DIM * K2;
constexpr int GTOK = 32;             // tokens per gemm block
constexpr int NGB = NTOK / GTOK;     // 1024 gemm tiles per cluster (worst case)
constexpr int NSEG = 64;             // classify blocks / list segments
constexpr int SEGW = 512;            // tokens per segment
constexpr int NCPY = NTOK / 8;       // 4096 copy blocks (8 tokens each)
constexpr int CROW = DIM + 4;        // C-tile row stride (words): 2-way alias only
constexpr int SMEM_BYTES = 16 * CROW * 4;  // 65792 > A-tile's 16896

typedef unsigned short u16;
typedef unsigned int u32;
typedef unsigned long long u64;
typedef __attribute__((ext_vector_type(8))) short bf16x8;
typedef __attribute__((ext_vector_type(4))) float f32x4;

__device__ __forceinline__ u16 f2bf(float f) {   // RNE f32 -> bf16
    u32 u = __builtin_bit_cast(u32, f);
    return (u16)((u + 0x7FFFu + ((u >> 16) & 1u)) >> 16);
}

// proj (f32 [DIM][K]) -> bf16 MFMA fragment order: chunk idx = (ntile*KS+kstep)*64+lane
template<int K>
__device__ __forceinline__ void cvt_body(int idx, const float* __restrict__ src,
                                         u16* __restrict__ dst) {
    constexpr int KS = K / 32;
    int lane = idx & 63;
    int rest = idx >> 6;
    int kstep = rest % KS;
    int ntile = rest / KS;
    int n = ntile * 16 + (lane & 15);
    int k = kstep * 32 + (lane >> 4) * 8;
    const float4* p = (const float4*)(src + (size_t)n * K + k);
    float4 a = p[0], b = p[1];
    u16 t[8] = {f2bf(a.x), f2bf(a.y), f2bf(a.z), f2bf(a.w),
                f2bf(b.x), f2bf(b.y), f2bf(b.z), f2bf(b.w)};
    *(int4*)(dst + (size_t)idx * 8) = *(const int4*)t;
}

// k1: blocks 0..63 classify (atomic-free segmented lists); 64..127 cvt proj1;
// 128..143 cvt proj2; 144.. copy cluster-0 rows. All roles <=64 regs, LDS ~64B
// -> 4 blocks/CU = 32 waves/CU for the HBM-bound copy stream.
__global__ __launch_bounds__(512, 8) void copyprep_k(const int* __restrict__ ids,
        const float* __restrict__ emb0, float* __restrict__ out,
        u16* __restrict__ list1, u16* __restrict__ list2,
        int* __restrict__ cnt1, int* __restrict__ cnt2,
        const float* __restrict__ proj1, const float* __restrict__ proj2,
        u16* __restrict__ projL1, u16* __restrict__ projL2) {
    int b = blockIdx.x;
    int tid = threadIdx.x;
    if (b >= 144) {
        // cluster 0 copy: 8 tokens per block, 512 threads x 4 float4 each
        int tbase = (b - 144) * 8;
        const float4* e4 = (const float4*)emb0;
        float4* o4 = (float4*)out;
        #pragma unroll
        for (int r = 0; r < 4; ++r) {
            int j = r * 512 + tid;          // float4 index within the 8 rows
            int tok = tbase + (j >> 8);     // 256 float4 per row
            int d4 = j & 255;
            int id = ids[tok];
            if (id < C1) {
                float4 v = make_float4(0.f, 0.f, 0.f, 0.f);
                if (id != PAD) v = e4[(size_t)id * 256 + d4];
                o4[(size_t)tok * 256 + d4] = v;
            }
        }
        return;
    }
    if (b >= 64) {
        if (b < 128) cvt_body<K1>((b - 64) * 512 + tid, proj1, projL1);
        else         cvt_body<K2>((b - 128) * 512 + tid, proj2, projL2);
        return;
    }
    __shared__ int woff1[8], woff2[8];
    int i = b * SEGW + tid;
    int id = ids[i];
    bool in1 = (id >= C1) & (id < C2);
    bool in2 = (id >= C2);
    u64 b1 = __ballot(in1);
    u64 b2 = __ballot(in2);
    int wave = tid >> 6, lane = tid & 63;
    if (lane == 0) { woff1[wave] = __popcll(b1); woff2[wave] = __popcll(b2); }
    __syncthreads();
    if (tid == 0) {
        int t1 = 0, t2 = 0;
        #pragma unroll
        for (int w = 0; w < 8; ++w) {
            int c1 = woff1[w]; woff1[w] = t1; t1 += c1;
            int c2 = woff2[w]; woff2[w] = t2; t2 += c2;
        }
        cnt1[b] = t1;                         // plain store: no init needed
        cnt2[b] = t2;
    }
    __syncthreads();
    u64 lt = (lane == 63) ? ~0ull >> 1 : (1ull << lane) - 1;
    if (in1) list1[b * SEGW + woff1[wave] + __popcll(b1 & lt)] = (u16)i;
    if (in2) list2[b * SEGW + woff2[wave] + __popcll(b2 & lt)] = (u16)i;
}

// gemm: 32 tokens x 1024 outputs per block, 8 waves; wave w owns n-tiles
// [w*8, w*8+8) x 2 m-tiles -> acc[2][8] = 64 AGPR. Token list reconstructed
// from segmented lists via prefix scan (wave 0) + binary search. A in LDS bf16
// (stride K+8); B fragment-ordered bf16 (1KB coalesced wave reads,
// L2-resident). C staged per-m-half through LDS -> coalesced 4KB-row stores.
template<int K>
__device__ __forceinline__ void gemm_body(int b, const int* __restrict__ ids,
        const float* __restrict__ emb, const u16* __restrict__ projL,
        const u16* __restrict__ list, const int* __restrict__ cnt,
        int base, float* __restrict__ out, char* __restrict__ sm,
        u16* __restrict__ s_tok, int* __restrict__ s_loc, int* __restrict__ s_pref) {
    constexpr int K8 = K / 8;
    constexpr int KS = K / 32;
    constexpr int LROW = K + 8;
    u16* A = (u16*)sm;
    float* Cs = (float*)sm;
    int t0 = b * GTOK;
    int tid = threadIdx.x;

    if (tid < 64) {                           // wave 0: inclusive scan of counts
        int c = cnt[tid];
        #pragma unroll
        for (int d = 1; d < 64; d <<= 1) {
            int y = __shfl_up(c, d);
            if ((tid & 63) >= d) c += y;
        }
        s_pref[tid + 1] = c;
        if (tid == 0) s_pref[0] = 0;
    }
    __syncthreads();
    int count = s_pref[NSEG];
    if (t0 >= count) return;
    int nt_valid = min(GTOK, count - t0);

    if (tid < GTOK) {
        int tokidx = 0, loc = -1;
        if (tid < nt_valid) {
            int g = t0 + tid;
            int lo = 0, hi = NSEG - 1;        // find seg: pref[s] <= g < pref[s+1]
            #pragma unroll
            for (int it = 0; it < 6; ++it) {
                int mid = (lo + hi + 1) >> 1;
                if (s_pref[mid] <= g) lo = mid; else hi = mid - 1;
            }
            tokidx = list[lo * SEGW + (g - s_pref[lo])];
            loc = ids[tokidx] - base;
            if (loc == PAD) loc = -1;         // padding row -> zeros
        }
        s_tok[tid] = (u16)tokidx;
        s_loc[tid] = loc;
    }
    __syncthreads();

    for (int c = tid; c < GTOK * K8; c += 512) {
        int m = c / K8, k8 = c % K8;
        int loc = s_loc[m];
        float4 v0 = make_float4(0.f,0.f,0.f,0.f), v1 = v0;
        if (loc >= 0) {
            const float4* p = (const float4*)(emb + (size_t)loc * K) + k8 * 2;
            v0 = p[0]; v1 = p[1];
        }
        u16 t[8] = {f2bf(v0.x), f2bf(v0.y), f2bf(v0.z), f2bf(v0.w),
                    f2bf(v1.x), f2bf(v1.y), f2bf(v1.z), f2bf(v1.w)};
        *(int4*)&A[m * LROW + k8 * 8] = *(const int4*)t;
    }
    __syncthreads();

    int wave = tid >> 6;
    int lane = tid & 63;
    int lr = lane & 15;
    int lk = (lane >> 4) * 8;
    const bf16x8* Bfrag = (const bf16x8*)projL;

    f32x4 acc[2][8] = {};
    for (int ks = 0; ks < KS; ++ks) {
        bf16x8 a0 = *(const bf16x8*)&A[lr * LROW + ks * 32 + lk];
        bf16x8 a1 = *(const bf16x8*)&A[(16 + lr) * LROW + ks * 32 + lk];
        #pragma unroll
        for (int nt = 0; nt < 8; ++nt) {
            bf16x8 bb = Bfrag[((size_t)((wave * 8 + nt) * KS + ks)) * 64 + lane];
            acc[0][nt] = __builtin_amdgcn_mfma_f32_16x16x32_bf16(a0, bb, acc[0][nt], 0, 0, 0);
            acc[1][nt] = __builtin_amdgcn_mfma_f32_16x16x32_bf16(a1, bb, acc[1][nt], 0, 0, 0);
        }
    }
    __syncthreads();     // A dead; reuse smem as C-tile

    // C/D layout (m89): col = lane&15, row-within-tile = (lane>>4)*4 + reg.
    int rbase = (lane >> 4) * 4;
    #pragma unroll
    for (int mh = 0; mh < 2; ++mh) {
        #pragma unroll
        for (int nt = 0; nt < 8; ++nt) {
            #pragma unroll
            for (int r = 0; r < 4; ++r)
                Cs[(rbase + r) * CROW + wave * 128 + nt * 16 + lr] = acc[mh][nt][r];
        }
        __syncthreads();
        #pragma unroll
        for (int k = 0; k < 8; ++k) {
            int idx = k * 512 + tid;         // f4 index in 16x256 tile
            int row = idx >> 8;
            int col4 = idx & 255;
            int trow = mh * 16 + row;
            if (trow < nt_valid) {
                const float* s = &Cs[row * CROW + col4 * 4];
                float4 v = make_float4(s[0], s[1], s[2], s[3]);
                *(float4*)(out + (size_t)s_tok[trow] * DIM + col4 * 4) = v;
            }
        }
        __syncthreads();
    }
}

__global__ __launch_bounds__(512, 4) void gemm_k(const int* __restrict__ ids,
        const float* __restrict__ emb1, const float* __restrict__ emb2,
        const u16* __restrict__ projL1, const u16* __restrict__ projL2,
        const u16* __restrict__ list1, const u16* __restrict__ list2,
        const int* __restrict__ cnt1, const int* __restrict__ cnt2,
        float* __restrict__ out) {
    __shared__ __align__(16) char smem[SMEM_BYTES];
    __shared__ u16 s_tok[GTOK];
    __shared__ int s_loc[GTOK];
    __shared__ int s_pref[NSEG + 1];
    // pairs [g1,g2] with per-pair rotation: (b + b/2) % 2 breaks the gcd(2,8)
    // XCD pinning (r14 lesson: -12% from role/XCD balance).
    int b = blockIdx.x;
    int stripe = b >> 1;
    int role = (b + stripe) & 1;
    if (role == 0)
        gemm_body<K1>(stripe, ids, emb1, projL1, list1, cnt1, C1, out,
                      smem, s_tok, s_loc, s_pref);
    else
        gemm_body<K2>(stripe, ids, emb2, projL2, list2, cnt2, C2, out,
                      smem, s_tok, s_loc, s_pref);
}

extern "C" void kernel_launch(void* const* d_in, const int* in_sizes, int n_in,
                              void* d_out, int out_size, void* d_ws, size_t ws_size,
                              hipStream_t stream) {
    const int*   ids   = (const int*)d_in[0];
    const float* emb0  = (const float*)d_in[1];
    const float* emb1  = (const float*)d_in[2];
    const float* emb2  = (const float*)d_in[3];
    const float* proj1 = (const float*)d_in[4];
    const float* proj2 = (const float*)d_in[5];
    float* out = (float*)d_out;

    int* cnt1   = (int*)d_ws;                            // [64]
    int* cnt2   = cnt1 + NSEG;                           // [64]
    u16* list1  = (u16*)(cnt2 + NSEG);                   // [64*512] segmented
    u16* list2  = list1 + NTOK;
    u16* projL1 = list2 + NTOK;                          // fragment-ordered bf16
    u16* projL2 = projL1 + NP1;

    copyprep_k<<<144 + NCPY, 512, 0, stream>>>(ids, emb0, out, list1, list2,
                                               cnt1, cnt2, proj1, proj2,
                                               projL1, projL2);
    gemm_k<<<NGB * 2, 512, 0, stream>>>(ids, emb1, emb2, projL1, projL2,
                                        list1, list2, cnt1, cnt2, out);
}

// Round 18
// 51.826 us; speedup vs baseline: 1.2603x; 1.2603x over previous
//
#include <hip/hip_runtime.h>

// AdaptiveEmbedding: VOCAB=50000, cutoffs [20000,40000], EMBED_DIM=1024, pad=1
// cluster 0: ids [0,20000)     -> emb0 [20000,1024], direct f32 gather
// cluster 1: ids [20000,40000) -> emb1 [20000,256]  @ proj1[1024,256]^T  (bf16 MFMA)
// cluster 2: ids [40000,50000) -> emb2 [10000,64]   @ proj2[1024,64]^T   (bf16 MFMA)
//
// Round 18 (r15 + prep-padding): prep_k grid padded to 512 blocks — blocks
// 144..511 each copy 2 cluster-0 chunks so the machine isn't idle during
// classify+cvt (r17's cooperative version failed graph capture; the kernel
// boundary provides the sync for free). fused_k (r15 champion): stripe-6
// rotated [g1,g2,c,c,c,c] (XCD balance, r14 -12%), gemm C staged through
// 66KB LDS -> coalesced 4KB-row stores, copy role skips pre-done chunks.

constexpr int NTOK = 8 * 4096;
constexpr int C1 = 20000;
constexpr int C2 = 40000;
constexpr int DIM = 1024;
constexpr int PAD = 1;
constexpr int K1 = 256, K2 = 64;
constexpr int NP1 = DIM * K1;
constexpr int NP2 = DIM * K2;
constexpr int GTOK = 32;             // tokens per gemm tile
constexpr int NB1 = NTOK / GTOK;     // 1024 stripes
constexpr int NSEG = 64;             // classify segments
constexpr int SEGW = 512;            // tokens per segment
constexpr int PREPB = 512;           // prep grid
constexpr int PRE = (PREPB - 144) * 2;   // 736 copy chunks done during prep
constexpr int CROW = DIM + 4;        // C-tile row stride (words): 2-way alias only
constexpr int SMEM_BYTES = 16 * CROW * 4;  // 65792 > A-tile's 16896

typedef unsigned short u16;
typedef unsigned int u32;
typedef unsigned long long u64;
typedef __attribute__((ext_vector_type(8))) short bf16x8;
typedef __attribute__((ext_vector_type(4))) float f32x4;

__device__ __forceinline__ u16 f2bf(float f) {   // RNE f32 -> bf16
    u32 u = __builtin_bit_cast(u32, f);
    return (u16)((u + 0x7FFFu + ((u >> 16) & 1u)) >> 16);
}

// proj (f32 [DIM][K]) -> bf16 MFMA fragment order: chunk idx = (ntile*KS+kstep)*64+lane
template<int K>
__device__ __forceinline__ void cvt_body(int idx, const float* __restrict__ src,
                                         u16* __restrict__ dst) {
    constexpr int KS = K / 32;
    int lane = idx & 63;
    int rest = idx >> 6;
    int kstep = rest % KS;
    int ntile = rest / KS;
    int n = ntile * 16 + (lane & 15);
    int k = kstep * 32 + (lane >> 4) * 8;
    const float4* p = (const float4*)(src + (size_t)n * K + k);
    float4 a = p[0], b = p[1];
    u16 t[8] = {f2bf(a.x), f2bf(a.y), f2bf(a.z), f2bf(a.w),
                f2bf(b.x), f2bf(b.y), f2bf(b.z), f2bf(b.w)};
    *(int4*)(dst + (size_t)idx * 8) = *(const int4*)t;
}

// one copy chunk = 8 consecutive tokens, 512 threads x 4 float4
__device__ __forceinline__ void copy_chunk(int cb, const int* __restrict__ ids,
        const float* __restrict__ emb0, float* __restrict__ out) {
    int tbase = cb * 8;
    int tid = threadIdx.x;
    const float4* e4 = (const float4*)emb0;
    float4* o4 = (float4*)out;
    #pragma unroll
    for (int r = 0; r < 4; ++r) {
        int j = r * 512 + tid;          // float4 index within the 8 rows
        int tok = tbase + (j >> 8);     // 256 float4 per row
        int d4 = j & 255;
        int id = ids[tok];
        if (id < C1) {
            float4 v = make_float4(0.f, 0.f, 0.f, 0.f);
            if (id != PAD) v = e4[(size_t)id * 256 + d4];
            o4[(size_t)tok * 256 + d4] = v;
        }
    }
}

// blocks 0..63 classify (atomic-free segmented lists, plain-stored counts);
// 64..127 cvt proj1; 128..143 cvt proj2; 144..511 copy 2 chunks each (keeps
// the machine busy during prep).
__global__ __launch_bounds__(512) void prep_k(const int* __restrict__ ids,
        const float* __restrict__ emb0, float* __restrict__ out,
        u16* __restrict__ list1, u16* __restrict__ list2,
        int* __restrict__ cnt1, int* __restrict__ cnt2,
        const float* __restrict__ proj1, const float* __restrict__ proj2,
        u16* __restrict__ projL1, u16* __restrict__ projL2) {
    int b = blockIdx.x;
    int tid = threadIdx.x;
    if (b >= 144) {
        int c0 = (b - 144) * 2;
        copy_chunk(c0, ids, emb0, out);
        copy_chunk(c0 + 1, ids, emb0, out);
        return;
    }
    if (b >= 64) {
        if (b < 128) cvt_body<K1>((b - 64) * 512 + tid, proj1, projL1);
        else         cvt_body<K2>((b - 128) * 512 + tid, proj2, projL2);
        return;
    }
    __shared__ int woff1[8], woff2[8];
    int i = b * SEGW + tid;
    int id = ids[i];
    bool in1 = (id >= C1) & (id < C2);
    bool in2 = (id >= C2);
    u64 b1 = __ballot(in1);
    u64 b2 = __ballot(in2);
    int wave = tid >> 6, lane = tid & 63;
    if (lane == 0) { woff1[wave] = __popcll(b1); woff2[wave] = __popcll(b2); }
    __syncthreads();
    if (tid == 0) {
        int t1 = 0, t2 = 0;
        #pragma unroll
        for (int w = 0; w < 8; ++w) {
            int c1 = woff1[w]; woff1[w] = t1; t1 += c1;
            int c2 = woff2[w]; woff2[w] = t2; t2 += c2;
        }
        cnt1[b] = t1;                         // plain store: no init needed
        cnt2[b] = t2;
    }
    __syncthreads();
    u64 lt = (lane == 63) ? ~0ull >> 1 : (1ull << lane) - 1;
    if (in1) list1[b * SEGW + woff1[wave] + __popcll(b1 & lt)] = (u16)i;
    if (in2) list2[b * SEGW + woff2[wave] + __popcll(b2 & lt)] = (u16)i;
}

// gemm: 32 tokens x 1024 outputs per block, 8 waves; wave w owns n-tiles
// [w*8, w*8+8) x 2 m-tiles -> acc[2][8] = 64 AGPR. Token list reconstructed
// from segmented lists via prefix scan (wave 0) + binary search. A in LDS bf16
// (stride K+8); B fragment-ordered bf16 (1KB coalesced wave reads,
// L2-resident). C staged per-m-half through LDS -> coalesced 4KB-row stores.
template<int K>
__device__ __forceinline__ void gemm_body(int b, const int* __restrict__ ids,
        const float* __restrict__ emb, const u16* __restrict__ projL,
        const u16* __restrict__ list, const int* __restrict__ cnt,
        int base, float* __restrict__ out, char* __restrict__ sm,
        u16* __restrict__ s_tok, int* __restrict__ s_loc, int* __restrict__ s_pref) {
    constexpr int K8 = K / 8;
    constexpr int KS = K / 32;
    constexpr int LROW = K + 8;
    u16* A = (u16*)sm;
    float* Cs = (float*)sm;
    int t0 = b * GTOK;
    int tid = threadIdx.x;

    if (tid < 64) {                           // wave 0: inclusive scan of counts
        int c = cnt[tid];
        #pragma unroll
        for (int d = 1; d < 64; d <<= 1) {
            int y = __shfl_up(c, d);
            if ((tid & 63) >= d) c += y;
        }
        s_pref[tid + 1] = c;
        if (tid == 0) s_pref[0] = 0;
    }
    __syncthreads();
    int count = s_pref[NSEG];
    if (t0 >= count) return;
    int nt_valid = min(GTOK, count - t0);

    if (tid < GTOK) {
        int tokidx = 0, loc = -1;
        if (tid < nt_valid) {
            int g = t0 + tid;
            int lo = 0, hi = NSEG - 1;        // find seg: pref[s] <= g < pref[s+1]
            #pragma unroll
            for (int it = 0; it < 6; ++it) {
                int mid = (lo + hi + 1) >> 1;
                if (s_pref[mid] <= g) lo = mid; else hi = mid - 1;
            }
            tokidx = list[lo * SEGW + (g - s_pref[lo])];
            loc = ids[tokidx] - base;
            if (loc == PAD) loc = -1;         // padding row -> zeros
        }
        s_tok[tid] = (u16)tokidx;
        s_loc[tid] = loc;
    }
    __syncthreads();

    for (int c = tid; c < GTOK * K8; c += 512) {
        int m = c / K8, k8 = c % K8;
        int loc = s_loc[m];
        float4 v0 = make_float4(0.f,0.f,0.f,0.f), v1 = v0;
        if (loc >= 0) {
            const float4* p = (const float4*)(emb + (size_t)loc * K) + k8 * 2;
            v0 = p[0]; v1 = p[1];
        }
        u16 t[8] = {f2bf(v0.x), f2bf(v0.y), f2bf(v0.z), f2bf(v0.w),
                    f2bf(v1.x), f2bf(v1.y), f2bf(v1.z), f2bf(v1.w)};
        *(int4*)&A[m * LROW + k8 * 8] = *(const int4*)t;
    }
    __syncthreads();

    int wave = tid >> 6;
    int lane = tid & 63;
    int lr = lane & 15;
    int lk = (lane >> 4) * 8;
    const bf16x8* Bfrag = (const bf16x8*)projL;

    f32x4 acc[2][8] = {};
    for (int ks = 0; ks < KS; ++ks) {
        bf16x8 a0 = *(const bf16x8*)&A[lr * LROW + ks * 32 + lk];
        bf16x8 a1 = *(const bf16x8*)&A[(16 + lr) * LROW + ks * 32 + lk];
        #pragma unroll
        for (int nt = 0; nt < 8; ++nt) {
            bf16x8 bb = Bfrag[((size_t)((wave * 8 + nt) * KS + ks)) * 64 + lane];
            acc[0][nt] = __builtin_amdgcn_mfma_f32_16x16x32_bf16(a0, bb, acc[0][nt], 0, 0, 0);
            acc[1][nt] = __builtin_amdgcn_mfma_f32_16x16x32_bf16(a1, bb, acc[1][nt], 0, 0, 0);
        }
    }
    __syncthreads();     // A dead; reuse smem as C-tile

    // C/D layout (m89): col = lane&15, row-within-tile = (lane>>4)*4 + reg.
    int rbase = (lane >> 4) * 4;
    #pragma unroll
    for (int mh = 0; mh < 2; ++mh) {
        #pragma unroll
        for (int nt = 0; nt < 8; ++nt) {
            #pragma unroll
            for (int r = 0; r < 4; ++r)
                Cs[(rbase + r) * CROW + wave * 128 + nt * 16 + lr] = acc[mh][nt][r];
        }
        __syncthreads();
        #pragma unroll
        for (int k = 0; k < 8; ++k) {
            int idx = k * 512 + tid;         // f4 index in 16x256 tile
            int row = idx >> 8;
            int col4 = idx & 255;
            int trow = mh * 16 + row;
            if (trow < nt_valid) {
                const float* s = &Cs[row * CROW + col4 * 4];
                float4 v = make_float4(s[0], s[1], s[2], s[3]);
                *(float4*)(out + (size_t)s_tok[trow] * DIM + col4 * 4) = v;
            }
        }
        __syncthreads();
    }
}

__global__ __launch_bounds__(512, 4) void fused_k(const int* __restrict__ ids,
        const float* __restrict__ emb0, const float* __restrict__ emb1,
        const float* __restrict__ emb2, const u16* __restrict__ projL1,
        const u16* __restrict__ projL2, const u16* __restrict__ list1,
        const u16* __restrict__ list2, const int* __restrict__ cnt1,
        const int* __restrict__ cnt2, float* __restrict__ out) {
    __shared__ __align__(16) char smem[SMEM_BYTES];
    __shared__ u16 s_tok[GTOK];
    __shared__ int s_loc[GTOK];
    __shared__ int s_pref[NSEG + 1];
    // stripe of 6 with per-stripe rotation (r14: -12%): covers all (XCD, role)
    // pairs; each stripe still holds each role exactly once.
    int b = blockIdx.x;
    int stripe = b / 6;
    int role = (b + stripe) % 6;
    if (role == 0) {
        gemm_body<K1>(stripe, ids, emb1, projL1, list1, cnt1, C1, out,
                      smem, s_tok, s_loc, s_pref);
        return;
    }
    if (role == 1) {
        gemm_body<K2>(stripe, ids, emb2, projL2, list2, cnt2, C2, out,
                      smem, s_tok, s_loc, s_pref);
        return;
    }
    // cluster 0 copy: skip chunks already done during prep
    int cb = stripe * 4 + (role - 2);
    if (cb >= PRE) copy_chunk(cb, ids, emb0, out);
}

extern "C" void kernel_launch(void* const* d_in, const int* in_sizes, int n_in,
                              void* d_out, int out_size, void* d_ws, size_t ws_size,
                              hipStream_t stream) {
    const int*   ids   = (const int*)d_in[0];
    const float* emb0  = (const float*)d_in[1];
    const float* emb1  = (const float*)d_in[2];
    const float* emb2  = (const float*)d_in[3];
    const float* proj1 = (const float*)d_in[4];
    const float* proj2 = (const float*)d_in[5];
    float* out = (float*)d_out;

    int* cnt1   = (int*)d_ws;                            // [64]
    int* cnt2   = cnt1 + NSEG;                           // [64]
    u16* list1  = (u16*)(cnt2 + NSEG);                   // [64*512] segmented
    u16* list2  = list1 + NTOK;
    u16* projL1 = list2 + NTOK;                          // fragment-ordered bf16
    u16* projL2 = projL1 + NP1;

    prep_k<<<PREPB, 512, 0, stream>>>(ids, emb0, out, list1, list2, cnt1, cnt2,
                                      proj1, proj2, projL1, projL2);
    fused_k<<<NB1 * 6, 512, 0, stream>>>(ids, emb0, emb1, emb2,
                                         projL1, projL2, list1, list2,
                                         cnt1, cnt2, out);
}